// Round 4
// baseline (44.983 us; speedup 1.0000x reference)
//
#include <hip/hip_runtime.h>
#include <hip/hip_bf16.h>
#include <math.h>

// MultiVariateAttention: out[b,u] = exp(mvn_logpdf(x[b]; mu[u], diag(s[u])))
// B = U = 4096, D = 16, fp32 in/out.
//
// Single fused kernel. Per-thread (UPT=2 units):
//   log2(out[b,u]) = sum_d x_d*(A1[u,d] + x_d*A2[u,d]) + bias[u]
//     A1 = log2e*mu*w, A2 = -0.5*log2e*w, w = 1/s^2
//     bias = -0.5*log2e*sum(mu^2 w) - sum(log2 s) - D*log2e*0.5*ln(2pi)
//   out = exp2(acc)   (v_exp_f32)
// Params computed inline (v_rcp_f32, v_log_f32) — no precompute kernel, no
// workspace, no inter-kernel drain. x staged in LDS so the b-loop contains
// no vmcnt waits: output stores stream to HBM un-awaited until kernel end.

#define TPB 256
#define DD 16
#define UPT 2      // u's per thread: params = 66 VGPR, float2 stores
#define BPB 32     // b rows per block -> grid (128,8) = 1024 blocks = 4/CU

static constexpr float L2E   = 1.4426950408889634f;   // log2(e)
static constexpr float HL2PI = 0.91893853320467274f;  // 0.5*ln(2*pi)

__global__ __launch_bounds__(TPB, 4) void mva_fused(
    const float* __restrict__ x,      // [B,1,D]
    const float* __restrict__ units,  // [U,D]
    const float* __restrict__ attn,   // [U,D,D]
    float* __restrict__ out, int U)
{
    const int u0 = blockIdx.y * (TPB * UPT) + threadIdx.x * UPT;
    const int b0 = blockIdx.x * BPB;

    // Stage x tile in LDS first; overlaps with the scattered param loads.
    __shared__ float xs[BPB][DD];
    for (int idx = threadIdx.x; idx < BPB * DD; idx += TPB) {
        xs[idx >> 4][idx & 15] = x[(size_t)b0 * DD + idx];
    }

    // Inline per-thread param computation for UPT consecutive units.
    float a1[UPT][DD], a2[UPT][DD], bias[UPT];
#pragma unroll
    for (int i = 0; i < UPT; ++i) {
        const int u = u0 + i;
        const float* ad = attn + (size_t)u * DD * DD;   // diag at d*(DD+1)
        const float* mu_p = units + (size_t)u * DD;
        float qn = 0.f;   // sum mu^2 * w
        float bl = 0.f;   // sum log2(s)
#pragma unroll
        for (int d = 0; d < DD; ++d) {
            float s  = fmaxf(ad[d * (DD + 1)], 1e-6f);
            float r  = __builtin_amdgcn_rcpf(s);        // v_rcp_f32
            float w  = r * r;
            float mu = mu_p[d];
            a1[i][d] = L2E * mu * w;
            a2[i][d] = -0.5f * L2E * w;
            qn = fmaf(mu * mu, w, qn);
            bl += __builtin_amdgcn_logf(s);             // v_log_f32 = log2
        }
        bias[i] = fmaf(-0.5f * L2E, qn, -(bl + DD * L2E * HL2PI));
    }
    __syncthreads();

#pragma unroll 2
    for (int b = 0; b < BPB; ++b) {
        float acc[UPT];
#pragma unroll
        for (int i = 0; i < UPT; ++i) acc[i] = bias[i];
#pragma unroll
        for (int j = 0; j < 4; ++j) {
            // Wave-uniform LDS address -> broadcast, conflict-free.
            float4 xv = *reinterpret_cast<const float4*>(&xs[b][4 * j]);
#pragma unroll
            for (int k = 0; k < 4; ++k) {
                float xd = (&xv.x)[k];
                int d = 4 * j + k;
#pragma unroll
                for (int i = 0; i < UPT; ++i) {
                    float t = fmaf(xd, a2[i][d], a1[i][d]);
                    acc[i]  = fmaf(xd, t, acc[i]);
                }
            }
        }
        float2 o;
        o.x = __builtin_amdgcn_exp2f(acc[0]);
        o.y = __builtin_amdgcn_exp2f(acc[1]);
        *reinterpret_cast<float2*>(out + (size_t)(b0 + b) * U + u0) = o;
    }
}

extern "C" void kernel_launch(void* const* d_in, const int* in_sizes, int n_in,
                              void* d_out, int out_size, void* d_ws, size_t ws_size,
                              hipStream_t stream) {
    const float* x     = (const float*)d_in[0];  // [B,1,D]
    const float* units = (const float*)d_in[1];  // [U,D]
    const float* attn  = (const float*)d_in[2];  // [U,D,D]
    float* out = (float*)d_out;

    const int B = in_sizes[0] / DD;  // 4096
    const int U = in_sizes[1] / DD;  // 4096

    dim3 grid(B / BPB, U / (TPB * UPT));  // (128, 8) = 1024 blocks
    mva_fused<<<grid, TPB, 0, stream>>>(x, units, attn, out, U);
}

// Round 5
// 31.972 us; speedup vs baseline: 1.4070x; 1.4070x over previous
//
#include <hip/hip_runtime.h>
#include <hip/hip_bf16.h>
#include <math.h>

// MultiVariateAttention: out[b,u] = exp(mvn_logpdf(x[b]; mu[u], diag(s[u])))
// B = U = 4096, D = 16, fp32 in/out.
//
// Two kernels (R3 structure — fused variant was latency-bound, R4 post-mortem):
//  1) precompute P[33][U]: A1,A2 (param-major, coalesced via LDS transpose), bias
//  2) main: log2(out) = sum_d x_d*(A1 + x_d*A2) + bias; out = exp2(acc)
// x staged in LDS so the b-loop has NO vmcnt waits -> stores stream freely.
// This round's lever: occupancy 50% -> 75% (BPB 16, 2048 blocks, 6 waves/SIMD).

#define TPB 256
#define DD 16
#define UPT 2      // u's per thread: params = 66 VGPR, float2 stores
#define BPB 16     // b rows per block -> grid (256,8) = 2048 blocks = 8/CU

static constexpr float L2E   = 1.4426950408889634f;   // log2(e)
static constexpr float HL2PI = 0.91893853320467274f;  // 0.5*ln(2*pi)

// P layout: [2*D+1][U]. rows 0..15 = A1[d], 16..31 = A2[d], 32 = bias.
// Block = 16 u x 16 d; results transposed through LDS for coalesced P writes.
__global__ __launch_bounds__(TPB) void mva_precompute(
    const float* __restrict__ units, const float* __restrict__ attn,
    float* __restrict__ P, int U)
{
    const int tid   = threadIdx.x;
    const int u_blk = blockIdx.x * (TPB / DD);   // 16 u per block
    const int ul    = tid >> 4, d = tid & 15;
    const int u     = u_blk + ul;

    float s  = fmaxf(attn[(size_t)u * DD * DD + d * (DD + 1)], 1e-6f);
    float w  = 1.f / (s * s);
    float mu = units[u * DD + d];
    float bn = -0.5f * mu * mu * w - logf(s);
    bn += __shfl_xor(bn, 1, 16);
    bn += __shfl_xor(bn, 2, 16);
    bn += __shfl_xor(bn, 4, 16);
    bn += __shfl_xor(bn, 8, 16);

    __shared__ float tile[2 * DD + 1][TPB / DD];
    tile[d][ul]      = L2E * mu * w;
    tile[DD + d][ul] = -0.5f * L2E * w;
    if (d == 0) tile[2 * DD][ul] = L2E * (bn - DD * HL2PI);
    __syncthreads();

    for (int i = tid; i < (2 * DD + 1) * (TPB / DD); i += TPB) {
        int row = i >> 4, col = i & 15;
        P[(size_t)row * U + u_blk + col] = tile[row][col];
    }
}

template <bool USE_WS>
__global__ __launch_bounds__(TPB, 6) void mva_main(
    const float* __restrict__ x,      // [B,1,D]
    const float* __restrict__ P,      // [33][U] when USE_WS
    const float* __restrict__ units,  // raw params when !USE_WS
    const float* __restrict__ attn,
    float* __restrict__ out, int U)
{
    const int u0 = blockIdx.y * (TPB * UPT) + threadIdx.x * UPT;
    const int b0 = blockIdx.x * BPB;

    // Issue the x-tile load first (BPB*DD == TPB: one element per thread).
    float xv_stage = x[(size_t)b0 * DD + threadIdx.x];

    float a1[UPT][DD], a2[UPT][DD], bias[UPT];
    if (USE_WS) {
#pragma unroll
        for (int d = 0; d < DD; ++d) {
            float2 v = *reinterpret_cast<const float2*>(P + (size_t)d * U + u0);
            a1[0][d] = v.x; a1[1][d] = v.y;
            float2 w = *reinterpret_cast<const float2*>(P + (size_t)(DD + d) * U + u0);
            a2[0][d] = w.x; a2[1][d] = w.y;
        }
        float2 bv = *reinterpret_cast<const float2*>(P + (size_t)(2 * DD) * U + u0);
        bias[0] = bv.x; bias[1] = bv.y;
    } else {
#pragma unroll
        for (int i = 0; i < UPT; ++i) {
            int u = u0 + i;
            float bn = 0.f;
#pragma unroll
            for (int d = 0; d < DD; ++d) {
                float s  = fmaxf(attn[(size_t)u * DD * DD + d * (DD + 1)], 1e-6f);
                float w  = 1.f / (s * s);
                float mu = units[u * DD + d];
                a1[i][d] = L2E * mu * w;
                a2[i][d] = -0.5f * L2E * w;
                bn += -0.5f * mu * mu * w - logf(s);
            }
            bias[i] = L2E * (bn - DD * HL2PI);
        }
    }

    __shared__ float xs[BPB][DD];
    xs[threadIdx.x >> 4][threadIdx.x & 15] = xv_stage;
    __syncthreads();

#pragma unroll 4
    for (int b = 0; b < BPB; ++b) {
        float acc[UPT];
#pragma unroll
        for (int i = 0; i < UPT; ++i) acc[i] = bias[i];
#pragma unroll
        for (int j = 0; j < 4; ++j) {
            // Wave-uniform LDS address -> broadcast, conflict-free.
            float4 xv = *reinterpret_cast<const float4*>(&xs[b][4 * j]);
#pragma unroll
            for (int k = 0; k < 4; ++k) {
                float xd = (&xv.x)[k];
                int d = 4 * j + k;
#pragma unroll
                for (int i = 0; i < UPT; ++i) {
                    float t = fmaf(xd, a2[i][d], a1[i][d]);
                    acc[i]  = fmaf(xd, t, acc[i]);
                }
            }
        }
        float2 o;
        o.x = __builtin_amdgcn_exp2f(acc[0]);
        o.y = __builtin_amdgcn_exp2f(acc[1]);
        *reinterpret_cast<float2*>(out + (size_t)(b0 + b) * U + u0) = o;
    }
}

extern "C" void kernel_launch(void* const* d_in, const int* in_sizes, int n_in,
                              void* d_out, int out_size, void* d_ws, size_t ws_size,
                              hipStream_t stream) {
    const float* x     = (const float*)d_in[0];  // [B,1,D]
    const float* units = (const float*)d_in[1];  // [U,D]
    const float* attn  = (const float*)d_in[2];  // [U,D,D]
    float* out = (float*)d_out;

    const int B = in_sizes[0] / DD;  // 4096
    const int U = in_sizes[1] / DD;  // 4096

    dim3 grid(B / BPB, U / (TPB * UPT));  // (256, 8) = 2048 blocks = 8/CU
    size_t pbytes = (size_t)(2 * DD + 1) * U * sizeof(float);

    if (ws_size >= pbytes) {
        float* P = (float*)d_ws;
        mva_precompute<<<U / (TPB / DD), TPB, 0, stream>>>(units, attn, P, U);
        mva_main<true><<<grid, TPB, 0, stream>>>(x, P, units, attn, out, U);
    } else {
        mva_main<false><<<grid, TPB, 0, stream>>>(x, nullptr, units, attn, out, U);
    }
}